// Round 8
// baseline (411.680 us; speedup 1.0000x reference)
//
#include <hip/hip_runtime.h>
#include <hip/hip_bf16.h>
#include <math.h>

// Problem constants
#define BB 4
#define NSEQ 4096
#define DD 1024
#define HH 16
#define HD 64
#define MROWS (BB * NSEQ)   // 16384

typedef __attribute__((ext_vector_type(8))) short short8;
typedef float v4f __attribute__((ext_vector_type(4)));
typedef unsigned short u16;

typedef __attribute__((address_space(1))) const void gconst_void;
typedef __attribute__((address_space(3))) void lds_void_t;

__device__ __constant__ int SHIFTS[24] = {0,1,2,3,4,6,8,12,16,24,32,48,64,96,128,192,256,384,512,768,1024,1536,2048,3072};

__device__ inline u16 f2bf(float f) {
    unsigned u = __float_as_uint(f);
    unsigned r = u + 0x7fffu + ((u >> 16) & 1u);
    return (u16)(r >> 16);
}
__device__ inline float bf2f(u16 h) {
    return __uint_as_float(((unsigned)h) << 16);
}
__device__ inline void gl2lds16(const u16* g, u16* l) {
    // async global->LDS DMA, 16B/lane; LDS dest = wave-uniform base + lane*16
    __builtin_amdgcn_global_load_lds((gconst_void*)g, (lds_void_t*)l, 16, 0, 0);
}

// ---------------- merged prep: x-cast, 3x transpose-cast, q-cast, bfuse, coef tables ----------------
// One launch replaces 7 independent prep kernels (round-6: -19us vs separate launches).
__device__ inline void tcast_dev(const float* __restrict__ W, long ldw, u16* __restrict__ WT, long ldt,
                                 int bx, int by, int tx, int ty, float (*tile)[33]) {
    long xg = (long)bx * 32 + tx;
    long y0 = (long)by * 32;
    for (int r = 0; r < 32; r += 8)
        tile[ty + r][tx] = W[(y0 + ty + r) * ldw + xg];
    __syncthreads();
    for (int r = 0; r < 32; r += 8)
        WT[((long)bx * 32 + ty + r) * ldt + y0 + tx] = f2bf(tile[tx][ty + r]);
}

__global__ __launch_bounds__(256) void prep_data_kernel(
    const float* __restrict__ x, const float* __restrict__ Wqkv,
    const float* __restrict__ Wgate, const float* __restrict__ Wout,
    const float* __restrict__ bqkv, const float* __restrict__ bgate,
    const float* __restrict__ scale_gain, const float* __restrict__ skip_w,
    const float* __restrict__ coupling,
    u16* __restrict__ xb, u16* __restrict__ WkvT, u16* __restrict__ WgateT,
    u16* __restrict__ WoutT, u16* __restrict__ WqC,
    float* __restrict__ bfuse, float* __restrict__ coefTab,
    float* __restrict__ coupS, float* __restrict__ swbuf) {
    __shared__ float tile[32][33];
    __shared__ float part[4][64];
    const int bid = blockIdx.x;
    const int t = threadIdx.x;
    const int tx = t & 31, ty = t >> 5;

    if (bid < 8192) {
        long i = ((long)bid * 256 + t) * 8;
        float4 f0 = *(const float4*)&x[i];
        float4 f1 = *(const float4*)&x[i + 4];
        u16 o[8];
        o[0] = f2bf(f0.x); o[1] = f2bf(f0.y); o[2] = f2bf(f0.z); o[3] = f2bf(f0.w);
        o[4] = f2bf(f1.x); o[5] = f2bf(f1.y); o[6] = f2bf(f1.z); o[7] = f2bf(f1.w);
        *(uint4*)&xb[i] = *(uint4*)o;
    } else if (bid < 10240) {
        int r = bid - 8192;                       // grid 64 x 32
        tcast_dev(Wqkv + 1024, 3072, WkvT, 1024, r & 63, r >> 6, tx, ty, tile);
    } else if (bid < 11264) {
        int r = bid - 10240;                      // grid 32 x 32
        tcast_dev(Wgate, 1024, WgateT, 1024, r & 31, r >> 5, tx, ty, tile);
    } else if (bid < 12288) {
        int r = bid - 11264;
        tcast_dev(Wout, 1024, WoutT, 1024, r & 31, r >> 5, tx, ty, tile);
    } else if (bid < 13312) {
        int r = bid - 12288;
        long i = ((long)r * 256 + t) * 4;
        int row = (int)(i >> 10);
        int col = (int)(i & 1023);
        float4 f = *(const float4*)&Wqkv[(long)row * 3072 + col];
        ushort4 o;
        o.x = f2bf(f.x); o.y = f2bf(f.y); o.z = f2bf(f.z); o.w = f2bf(f.w);
        *(ushort4*)&WqC[i] = o;
    } else if (bid < 13328) {
        int r = bid - 13312;
        int nloc = t & 63, strip = t >> 6;
        int n = r * 64 + nloc;
        float s = 0.f;
        for (int j = strip * 256; j < strip * 256 + 256; j++)
            s += bqkv[j] * Wgate[(long)j * 1024 + n];
        part[strip][nloc] = s;
        __syncthreads();
        if (strip == 0)
            bfuse[n] = bgate[n] + part[0][nloc] + part[1][nloc] + part[2][nloc] + part[3][nloc];
    } else {
        const float D4T[4] = {0.4829629131445341f, 0.8365163037378079f, 0.2241438680420134f, -0.1294095225512604f};
        if (t < 2) swbuf[t] = 1.0f / (1.0f + expf(-skip_w[t]));
        if (t < 16) {
            float m = -1e30f;
            for (int j = 0; j < 16; j++) m = fmaxf(m, coupling[t * 16 + j]);
            float s = 0.f, e[16];
            for (int j = 0; j < 16; j++) { e[j] = expf(coupling[t * 16 + j] - m); s += e[j]; }
            for (int j = 0; j < 16; j++) coupS[t * 16 + j] = e[j] / s;
            float g[11];
            m = -1e30f;
            for (int j = 0; j < 11; j++) m = fmaxf(m, scale_gain[j * 16 + t]);
            s = 0.f;
            for (int j = 0; j < 11; j++) { g[j] = expf(scale_gain[j * 16 + t] - m); s += g[j]; }
            for (int j = 0; j < 11; j++) g[j] /= s;
            float cf[24];
            for (int i = 0; i < 24; i++) cf[i] = 0.f;
            for (int j = 0; j < 11; j++) {
                int d = 1 << j;
                for (int tt = 0; tt < 4; tt++) {
                    int sh = (3 - tt) * d;
                    for (int i = 0; i < 24; i++) {
                        if (SHIFTS[i] == sh) { cf[i] += g[j] * D4T[tt]; break; }
                    }
                }
            }
            for (int i = 0; i < 24; i++) coefTab[t * 24 + i] = cf[i];
        }
    }
}

// ---------------- gemm64: small 1024^3 GEMM, 64x64 tile, 4 waves, bf16 out ----------------
__global__ __launch_bounds__(256) void gemm64(const u16* __restrict__ A, long lda,
                                              const u16* __restrict__ BT, long ldb, int K,
                                              u16* __restrict__ C, long ldc) {
    __shared__ u16 As[64 * 32];
    __shared__ u16 Bs[64 * 32];
    const int tid = threadIdx.x;
    const int wv = tid >> 6, lane = tid & 63;
    const int wm = wv >> 1, wn = wv & 1;          // 2x2 wave grid; wave tile 32x32
    const int lrow = lane & 15, kq = lane >> 4;
    const long m0 = (long)blockIdx.y * 64, n0 = (long)blockIdx.x * 64;

    const int srow = wv * 16 + (lane >> 2);
    const int scol = ((lane & 3) ^ ((lane >> 3) & 3)) * 8;   // key = (srow>>1)&3 = (lane>>3)&3
    const u16* gA = A + (m0 + srow) * lda + scol;
    const u16* gB = BT + (n0 + srow) * ldb + scol;
    u16* la = &As[wv * 16 * 32];
    u16* lb = &Bs[wv * 16 * 32];

    const int acol = (kq ^ ((lrow >> 1) & 3)) * 8;
    v4f acc[2][2];
#pragma unroll
    for (int i = 0; i < 2; i++)
#pragma unroll
        for (int j = 0; j < 2; j++) acc[i][j] = (v4f){0.f, 0.f, 0.f, 0.f};

    for (int k0 = 0; k0 < K; k0 += 32) {
        gl2lds16(gA + k0, la);
        gl2lds16(gB + k0, lb);
        __syncthreads();
        short8 af[2], bf[2];
#pragma unroll
        for (int i = 0; i < 2; i++) af[i] = *(const short8*)&As[(wm * 32 + i * 16 + lrow) * 32 + acol];
#pragma unroll
        for (int j = 0; j < 2; j++) bf[j] = *(const short8*)&Bs[(wn * 32 + j * 16 + lrow) * 32 + acol];
#pragma unroll
        for (int im = 0; im < 2; im++)
#pragma unroll
            for (int in = 0; in < 2; in++)
                acc[im][in] = __builtin_amdgcn_mfma_f32_16x16x32_bf16(af[im], bf[in], acc[im][in], 0, 0, 0);
        __syncthreads();
    }
#pragma unroll
    for (int im = 0; im < 2; im++) {
#pragma unroll
        for (int in = 0; in < 2; in++) {
            long row = m0 + wm * 32 + im * 16 + kq * 4;
            long col = n0 + wn * 32 + in * 16 + lrow;
#pragma unroll
            for (int i = 0; i < 4; i++)
                C[(row + i) * ldc + col] = f2bf(acc[im][in][i]);
        }
    }
}

// ======== pipelined 256x256 GEMM engine (single-phase + counted vmcnt; schedule axis closed) ========
// 8 waves (2M x 4N), BK=32, 4-deep LDS tile rotation (128 KB), counted vmcnt
// (never 0 in steady state), one raw s_barrier per K-step, setprio around MFMA.
//
// CMODE=2 dataflow (round 7/8):
//  - k columns (n0<1024): NO stores (dead); in-register kmag only.
//  - v columns: ROUND-8 -- transpose through the (now free) 128KB smem into
//    field_t layout [bh][cg][n][4], then 16B/lane coalesced copy-out.
//    Round-7's direct scatter (2B/lane stores hitting 16 lines/inst) cost
//    +50us on the fused GEMM (190us, MfmaUtil 23%) -- coalescing is a
//    per-instruction property. Block output = 4 heads x 16 cg x 256 n x 4 ch
//    x 2B = 128KB = exactly smem. Post-loop smem reuse is race-free (final
//    barrier follows full vm/lgkm drain).
//  - gate columns: row-major coalesced stores (unchanged).
#define WAITV(N) asm volatile("s_waitcnt vmcnt(" #N ")" ::: "memory")

template <int CMODE>   // 0 = fp32 out + bias; 2 = fused field_t/gate epilogue (+kmag for k-cols)
__global__ __launch_bounds__(512, 2) void gemm256(const u16* __restrict__ A, long lda,
                                                  const u16* __restrict__ BT, long ldb, int K,
                                                  const float* __restrict__ bias,
                                                  const float* __restrict__ bias2,
                                                  void* __restrict__ C0, void* __restrict__ C1,
                                                  long ldc, float* __restrict__ kmagOut) {
    __shared__ u16 smem[4 * 2 * 8192];   // 128 KB: [buf 0..3][A|B][256 rows x 32 k]
    const int tid = threadIdx.x;
    const int wv = tid >> 6, lane = tid & 63;
    const int wm = wv >> 2, wn = wv & 3;          // 2 x 4 wave grid; wave tile 128 x 64
    const int lrow = lane & 15, kq = lane >> 4;

    // XCD-aware bijective swizzle of the dispatch-linear block id (measured neutral; kept)
    const int nwg = gridDim.x * gridDim.y;        // 768 (fused) or 256 (out): % 8 == 0
    const int lbid = blockIdx.y * gridDim.x + blockIdx.x;
    const int swz = (lbid & 7) * (nwg >> 3) + (lbid >> 3);
    const int bx = swz % gridDim.x, by = swz / gridDim.x;
    const long m0 = (long)by * 256, n0 = (long)bx * 256;

    // staging: wave wv owns rows wv*32 .. wv*32+31 of both tiles (2 calls of 16 rows each).
    // Global source column is PRE-SWIZZLED; LDS dest stays linear (gl2lds constraint).
    const int srow = wv * 32 + (lane >> 2);
    const int scol = ((lane & 3) ^ ((lane >> 3) & 3)) * 8;   // sg = (lane&3) ^ ((srow>>1)&3)
    const u16* gA0 = A + (m0 + srow) * lda + scol;
    const u16* gA1 = gA0 + 16 * lda;              // +16 rows: (row>>1)&3 unchanged
    const u16* gB0 = BT + (n0 + srow) * ldb + scol;
    const u16* gB1 = gB0 + 16 * ldb;
    const int sb = wv * 32 * 32;                  // u16 offset of wave's stage region in a tile

    // fragment read: undo the swizzle
    const int acol = (kq ^ ((lrow >> 1) & 3)) * 8;
    const int aoff = (wm * 128 + lrow) * 32 + acol;
    const int boff = (wn * 64 + lrow) * 32 + acol;

    v4f acc[8][4];
#pragma unroll
    for (int i = 0; i < 8; i++)
#pragma unroll
        for (int j = 0; j < 4; j++) acc[i][j] = (v4f){0.f, 0.f, 0.f, 0.f};

    const int NT = K >> 5;   // K-tiles of 32 (requires K >= 96; K == 1024 here)

#define STAGE256(tt) {                                              \
        const int _kk = (tt) << 5;                                  \
        u16* _p = &smem[(((tt) & 3) * 2) * 8192 + sb];              \
        gl2lds16(gA0 + _kk, _p);                                    \
        gl2lds16(gA1 + _kk, _p + 512);                              \
        gl2lds16(gB0 + _kk, _p + 8192);                             \
        gl2lds16(gB1 + _kk, _p + 8192 + 512); }

    STAGE256(0)
    STAGE256(1)
    STAGE256(2)
    WAITV(8);                        // 12 issued, <=8 outstanding -> tile 0 landed
    __builtin_amdgcn_s_barrier();

    for (int t = 0; t < NT; ++t) {
        if (t + 3 < NT) STAGE256(t + 3)          // issue-early; buffer freed at end of t-1
        const u16* Ab = &smem[((t & 3) * 2) * 8192];
        const u16* Bb = Ab + 8192;
        short8 af[8], bf[4];
#pragma unroll
        for (int i = 0; i < 8; i++) af[i] = *(const short8*)&Ab[aoff + i * 512];
#pragma unroll
        for (int j = 0; j < 4; j++) bf[j] = *(const short8*)&Bb[boff + j * 512];
        __builtin_amdgcn_s_setprio(1);
#pragma unroll
        for (int i = 0; i < 8; i++)
#pragma unroll
            for (int j = 0; j < 4; j++)
                acc[i][j] = __builtin_amdgcn_mfma_f32_16x16x32_bf16(af[i], bf[j], acc[i][j], 0, 0, 0);
        __builtin_amdgcn_s_setprio(0);
        if (t + 3 < NT)      { WAITV(8); }       // tiles t+2,t+3 may stay in flight
        else if (t + 2 < NT) { WAITV(4); }       // only t+2 issued after t+1
        else if (t + 1 < NT) { WAITV(0); }       // nothing issued after t+1: drain
        __builtin_amdgcn_s_barrier();
    }
#undef STAGE256

    // ---- epilogue ----
    if (CMODE == 0) {
        float* C = (float*)C0;
#pragma unroll
        for (int im = 0; im < 8; im++) {
#pragma unroll
            for (int in = 0; in < 4; in++) {
                long row = m0 + wm * 128 + im * 16 + kq * 4;
                long col = n0 + wn * 64 + in * 16 + lrow;
                float bv = bias ? bias[col] : 0.f;
#pragma unroll
                for (int i = 0; i < 4; i++)
                    C[(row + i) * ldc + col] = acc[im][in][i] + bv;
            }
        }
    } else {
        u16* fieldT = (u16*)C0;
        u16* gateC = (u16*)C1;
        const bool isGate = (n0 >= 2048);        // BN=256 aligns with the 2048 split
        if (isGate) {
#pragma unroll
            for (int im = 0; im < 8; im++) {
#pragma unroll
                for (int in = 0; in < 4; in++) {
                    long row = m0 + wm * 128 + im * 16 + kq * 4;
                    long gc = n0 + wn * 64 + in * 16 + lrow - 2048;
                    float bv = bias2[gc];
#pragma unroll
                    for (int i = 0; i < 4; i++) {
                        float sgm = 1.0f / (1.0f + expf(-(acc[im][in][i] + bv)));
                        gateC[(row + i) * 1024 + gc] = f2bf(sgm);
                    }
                }
            }
        } else if (n0 < 1024) {
            // k columns: kmag ONLY (k stores are dead -- nothing reads them).
            // Wave wn owns exactly one head's 64 cols.
            float bvv[4];
#pragma unroll
            for (int in = 0; in < 4; in++) bvv[in] = bias[n0 + wn * 64 + in * 16 + lrow];
            const int h_g = (int)(n0 >> 6) + wn;
#pragma unroll
            for (int im = 0; im < 8; im++) {
                long row = m0 + wm * 128 + im * 16 + kq * 4;
                float ss0 = 0.f, ss1 = 0.f, ss2 = 0.f, ss3 = 0.f;
#pragma unroll
                for (int in = 0; in < 4; in++) {
                    float v0 = acc[im][in][0] + bvv[in];
                    float v1 = acc[im][in][1] + bvv[in];
                    float v2 = acc[im][in][2] + bvv[in];
                    float v3 = acc[im][in][3] + bvv[in];
                    ss0 += v0 * v0; ss1 += v1 * v1; ss2 += v2 * v2; ss3 += v3 * v3;
                }
                // reduce over the 16 lrow lanes (shfl_xor masks 1,2,4,8 stay within the kq group)
#pragma unroll
                for (int m = 1; m <= 8; m <<= 1) {
                    ss0 += __shfl_xor(ss0, m, 64);
                    ss1 += __shfl_xor(ss1, m, 64);
                    ss2 += __shfl_xor(ss2, m, 64);
                    ss3 += __shfl_xor(ss3, m, 64);
                }
                if (lrow == 0) {
                    int b = (int)(row >> 12);
                    int n = (int)(row & 4095);
                    float4 o4 = make_float4(sqrtf(ss0), sqrtf(ss1), sqrtf(ss2), sqrtf(ss3));
                    *(float4*)&kmagOut[((long)b * HH + h_g) * NSEQ + n] = o4;
                }
            }
        } else {
            // v columns: transpose through smem (free after K-loop) into field_t
            // layout, then coalesced 16B/lane copy-out.
            // LDS logical layout: [cidx=h_local*16+cg][n_local 0..255][c 0..3] u16.
            const int vc0 = (int)(n0 - 1024);
            const int h0 = vc0 >> 6;
            const int b = (int)(m0 >> 12);
            const int nn0 = (int)(m0 & 4095);
            float bvv[4];
#pragma unroll
            for (int in = 0; in < 4; in++) bvv[in] = bias[1024 + vc0 + wn * 64 + in * 16 + lrow];
            const int cpart = (lrow >> 2);       // sub-cg from lane row
            const int cch = (lrow & 3);          // channel within cg
#pragma unroll
            for (int im = 0; im < 8; im++) {
                int nl0 = wm * 128 + im * 16 + kq * 4;
#pragma unroll
                for (int in = 0; in < 4; in++) {
                    int cidx = wn * 16 + in * 4 + cpart;
                    u16* p = &smem[(cidx * 256 + nl0) * 4 + cch];
#pragma unroll
                    for (int i = 0; i < 4; i++)
                        p[i * 4] = f2bf(acc[im][in][i] + bvv[in]);
                }
            }
            __syncthreads();
#pragma unroll
            for (int it = 0; it < 16; it++) {
                int off = (it * 512 + tid) * 8;   // u16 index into the 64K-u16 LDS
                int cidx = off >> 10;             // h_local*16+cg
                int nl = (off & 1023) >> 2;       // first n_local of this 16B (even)
                u16* dst = fieldT + (((long)(b * 16 + h0 + (cidx >> 4)) * 16 + (cidx & 15)) * NSEQ + nn0 + nl) * 4;
                *(uint4*)dst = *(uint4*)&smem[off];
            }
        }
    }
}

// ---------------- pyramid: 24-tap merged dilated causal conv + fused sparse skips + kmag scale ----------------
// Stage applies field = v * kmag (kmag coalesced float2 per 16B of v) -- replaces foldv.
// skip taps at n-512 / n-1024 are this thread's own outputs at i-1 / i-2
// (n = tid + i*512, 512 threads) -> pure register history, fp32 precision.
__global__ __launch_bounds__(512) void pyramid_kernel(const u16* __restrict__ field_t,
                                                      const float* __restrict__ kmag,
                                                      const float* __restrict__ coefTab,
                                                      const float* __restrict__ swbuf,
                                                      u16* __restrict__ accp) {
    __shared__ u16 lds4[NSEQ * 4];  // 32KB: 4096 rows x 4 channels, bf16
    int blk = blockIdx.x;
    int bh = blk >> 4;       // 0..63 : b*16+h
    int cg = blk & 15;       // channel group of 4
    int hd0 = cg * 4;
    int h = bh & 15;
    int tid = threadIdx.x;

    float cf[24];
#pragma unroll
    for (int i = 0; i < 24; i++) cf[i] = coefTab[h * 24 + i];
    float sw0 = swbuf[0], sw1 = swbuf[1];

    // stage: contiguous 32 KB copy (16B per lane) with kmag scale (2 n-positions per 16B)
    const u16* src = field_t + ((long)bh * 16 + cg) * NSEQ * 4;
    const float* kmb = kmag + (long)bh * NSEQ;
#pragma unroll
    for (int k = 0; k < 4; k++) {
        long e = ((long)k * 512 + tid) * 8;
        uint4 raw = *(const uint4*)&src[e];
        int np = (int)(e >> 2);                   // first of the 2 n-positions in this 16B
        float2 km = *(const float2*)&kmb[np];
        u16 in8[8], o8[8];
        *(uint4*)in8 = raw;
#pragma unroll
        for (int q = 0; q < 4; q++) o8[q] = f2bf(bf2f(in8[q]) * km.x);
#pragma unroll
        for (int q = 4; q < 8; q++) o8[q] = f2bf(bf2f(in8[q]) * km.y);
        *(uint4*)&lds4[e] = *(uint4*)o8;
    }
    __syncthreads();

    u16* dst = accp + (long)bh * NSEQ * HD + hd0;
    float p1x = 0.f, p1y = 0.f, p1z = 0.f, p1w = 0.f;   // y at i-1 (n-512)
    float p2x = 0.f, p2y = 0.f, p2z = 0.f, p2w = 0.f;   // y at i-2 (n-1024)
    for (int i = 0; i < 8; i++) {
        int n = tid + i * 512;
        float ax = 0.f, ay = 0.f, az = 0.f, aw = 0.f;
#pragma unroll
        for (int tp = 0; tp < 24; tp++) {
            int s = SHIFTS[tp];
            if (n >= s) {
                const ushort4 f = *(const ushort4*)&lds4[(n - s) * 4];
                float c = cf[tp];
                ax += c * bf2f(f.x); ay += c * bf2f(f.y);
                az += c * bf2f(f.z); aw += c * bf2f(f.w);
            }
        }
        float ox = ax + sw0 * p1x + sw1 * p2x;
        float oy = ay + sw0 * p1y + sw1 * p2y;
        float oz = az + sw0 * p1z + sw1 * p2z;
        float ow = aw + sw0 * p1w + sw1 * p2w;
        ushort4 o;
        o.x = f2bf(ox); o.y = f2bf(oy); o.z = f2bf(oz); o.w = f2bf(ow);
        *(ushort4*)&dst[(long)n * HD] = o;
        p2x = p1x; p2y = p1y; p2z = p1z; p2w = p1w;
        p1x = ax;  p1y = ay;  p1z = az;  p1w = aw;
    }
}

// ---------------- couple: head coupling + gate -> A3 bf16 (skips already in accp) ----------------
__global__ __launch_bounds__(256) void couple_kernel(const u16* __restrict__ accp,
                                                     const u16* __restrict__ gate,
                                                     const float* __restrict__ coupS,
                                                     u16* __restrict__ A3) {
    __shared__ float tmp[DD];
    __shared__ float cp[256];
    int row = blockIdx.x;
    int b = row >> 12;
    int n = row & 4095;
    int tid = threadIdx.x;
    cp[tid] = coupS[tid];

    int e = tid * 4;
    int j = e >> 6;      // head
    int hd = e & 63;
    const u16* base = accp + (((long)b * HH + j) * NSEQ + n) * HD + hd;
    ushort4 v0 = *(const ushort4*)base;
    tmp[e] = bf2f(v0.x); tmp[e + 1] = bf2f(v0.y);
    tmp[e + 2] = bf2f(v0.z); tmp[e + 3] = bf2f(v0.w);
    __syncthreads();

    float ox = 0.f, oy = 0.f, oz = 0.f, ow = 0.f;
#pragma unroll
    for (int jj = 0; jj < 16; jj++) {
        float c = cp[j * 16 + jj];
        ox += c * tmp[jj * 64 + hd];
        oy += c * tmp[jj * 64 + hd + 1];
        oz += c * tmp[jj * 64 + hd + 2];
        ow += c * tmp[jj * 64 + hd + 3];
    }
    const ushort4 g = *(const ushort4*)&gate[(long)row * DD + e];
    ox *= bf2f(g.x); oy *= bf2f(g.y); oz *= bf2f(g.z); ow *= bf2f(g.w);
    ushort4 o;
    o.x = f2bf(ox); o.y = f2bf(oy); o.z = f2bf(oz); o.w = f2bf(ow);
    *(ushort4*)&A3[(long)row * DD + e] = o;
}

// ---------------- launch ----------------
extern "C" void kernel_launch(void* const* d_in, const int* in_sizes, int n_in,
                              void* d_out, int out_size, void* d_ws, size_t ws_size,
                              hipStream_t stream) {
    const float* x        = (const float*)d_in[0];   // [16384][1024]
    const float* Wqkv     = (const float*)d_in[1];   // [1024][3072]
    const float* bqkv     = (const float*)d_in[2];   // [3072]
    const float* Wout     = (const float*)d_in[3];   // [1024][1024]
    const float* bout     = (const float*)d_in[4];   // [1024]
    const float* Wgate    = (const float*)d_in[5];   // [1024][1024]
    const float* bgate    = (const float*)d_in[6];   // [1024]
    const float* scale_g  = (const float*)d_in[7];   // [11][16]
    const float* skip_w   = (const float*)d_in[8];   // [2]
    const float* coupling = (const float*)d_in[9];   // [16][16]

    char* ws = (char*)d_ws;
    size_t off = 0;
    auto alloc = [&](size_t bytes) { char* p = ws + off; off += (bytes + 255) & ~(size_t)255; return p; };

    u16*   kvreg   = (u16*)alloc((size_t)MROWS * 2048 * 2);         // 67.1 MB: lo=field_t, hi=A3
    u16*   gate    = (u16*)alloc((size_t)MROWS * DD * 2);           // 33.6 MB
    u16*   reg1    = (u16*)alloc((size_t)BB * HH * NSEQ * HD * 2);  // 33.6 MB: xb, then accp
    u16*   WkvT    = (u16*)alloc((size_t)2048 * 1024 * 2);          // 4.2 MB   } contiguous: fused B^T
    u16*   WfuseT  = (u16*)alloc((size_t)1024 * 1024 * 2);          // 2.1 MB   } rows 2048..3071
    u16*   WgateT  = (u16*)alloc((size_t)1024 * 1024 * 2);          // 2.1 MB
    u16*   WoutT   = (u16*)alloc((size_t)1024 * 1024 * 2);          // 2.1 MB
    u16*   WqC     = (u16*)alloc((size_t)1024 * 1024 * 2);          // 2.1 MB
    float* kmag    = (float*)alloc((size_t)BB * HH * NSEQ * 4);     // 1.0 MB
    float* bfuse   = (float*)alloc(1024 * 4);
    float* coefT   = (float*)alloc(16 * 24 * 4);
    float* coupS   = (float*)alloc(256 * 4);
    float* swbuf   = (float*)alloc(2 * 4);
    // aliases / lifetimes:
    u16*   fieldT = kvreg;                               // written by gemm256<2> (v-cols)
    u16*   A3     = kvreg + (size_t)BB * HH * NSEQ * HD; // kv hi half
    u16*   xb     = reg1;                                // x cast; dead after gemm256<2>
    u16*   accp   = reg1;                                // pyramid out (xb dead)
    // total ~147 MB

    // 0) merged prep: x-cast, weight transposes/casts, bfuse, coef tables (one launch)
    prep_data_kernel<<<13329, 256, 0, stream>>>(x, Wqkv, Wgate, Wout, bqkv, bgate,
                                                scale_g, skip_w, coupling,
                                                xb, WkvT, WgateT, WoutT, WqC,
                                                bfuse, coefT, coupS, swbuf);

    // 1) WfuseT[g][k_in] = sum_j WgateT[g][j] * WqC[k_in][j]  (= (Wqkv_q @ Wgate)^T)
    gemm64<<<dim3(16, 16), 256, 0, stream>>>(WgateT, 1024, WqC, 1024, 1024, WfuseT, 1024);

    // 2) fused: k->kmag only; v->field_t layout via LDS transpose (+bias); gate->sigmoid
    gemm256<2><<<dim3(12, 64), 512, 0, stream>>>(xb, 1024, WkvT, 1024, 1024,
                                                 bqkv + 1024, bfuse, fieldT, gate, 0, kmag);

    // 3) pyramid (kmag scale in stage + 24 merged taps + fused sparse skips) -> accp (xb dead)
    pyramid_kernel<<<BB * HH * 16, 512, 0, stream>>>(fieldT, kmag, coefT, swbuf, accp);

    // 4) head coupling + gating -> A3 (kv hi; fieldT dead after pyramid)
    couple_kernel<<<MROWS, 256, 0, stream>>>(accp, gate, coupS, A3);

    // 5) out = A3 @ Wout + bout  (fp32 out)
    gemm256<0><<<dim3(4, 64), 512, 0, stream>>>(A3, 1024, WoutT, 1024, 1024,
                                                bout, (const float*)nullptr, (float*)d_out, nullptr,
                                                1024, (float*)nullptr);
}

// Round 9
// 404.979 us; speedup vs baseline: 1.0165x; 1.0165x over previous
//
#include <hip/hip_runtime.h>
#include <hip/hip_bf16.h>
#include <math.h>

// Problem constants
#define BB 4
#define NSEQ 4096
#define DD 1024
#define HH 16
#define HD 64
#define MROWS (BB * NSEQ)   // 16384

typedef __attribute__((ext_vector_type(8))) short short8;
typedef float v4f __attribute__((ext_vector_type(4)));
typedef unsigned short u16;

typedef __attribute__((address_space(1))) const void gconst_void;
typedef __attribute__((address_space(3))) void lds_void_t;

__device__ __constant__ int SHIFTS[24] = {0,1,2,3,4,6,8,12,16,24,32,48,64,96,128,192,256,384,512,768,1024,1536,2048,3072};

__device__ inline u16 f2bf(float f) {
    unsigned u = __float_as_uint(f);
    unsigned r = u + 0x7fffu + ((u >> 16) & 1u);
    return (u16)(r >> 16);
}
__device__ inline float bf2f(u16 h) {
    return __uint_as_float(((unsigned)h) << 16);
}
__device__ inline void gl2lds16(const u16* g, u16* l) {
    // async global->LDS DMA, 16B/lane; LDS dest = wave-uniform base + lane*16
    __builtin_amdgcn_global_load_lds((gconst_void*)g, (lds_void_t*)l, 16, 0, 0);
}

// ---------------- prep_weights: transpose-casts, q-cast, bfuse, coef tables ----------------
// Small launch (5137 blocks); runs before the merged gemm64+xcast kernel.
__device__ inline void tcast_dev(const float* __restrict__ W, long ldw, u16* __restrict__ WT, long ldt,
                                 int bx, int by, int tx, int ty, float (*tile)[33]) {
    long xg = (long)bx * 32 + tx;
    long y0 = (long)by * 32;
    for (int r = 0; r < 32; r += 8)
        tile[ty + r][tx] = W[(y0 + ty + r) * ldw + xg];
    __syncthreads();
    for (int r = 0; r < 32; r += 8)
        WT[((long)bx * 32 + ty + r) * ldt + y0 + tx] = f2bf(tile[tx][ty + r]);
}

__global__ __launch_bounds__(256) void prep_weights_kernel(
    const float* __restrict__ Wqkv, const float* __restrict__ Wgate, const float* __restrict__ Wout,
    const float* __restrict__ bqkv, const float* __restrict__ bgate,
    const float* __restrict__ scale_gain, const float* __restrict__ skip_w,
    const float* __restrict__ coupling,
    u16* __restrict__ WkvT, u16* __restrict__ WgateT, u16* __restrict__ WoutT, u16* __restrict__ WqC,
    float* __restrict__ bfuse, float* __restrict__ coefTab,
    float* __restrict__ coupS, float* __restrict__ swbuf) {
    __shared__ float tile[32][33];
    __shared__ float part[4][64];
    const int bid = blockIdx.x;
    const int t = threadIdx.x;
    const int tx = t & 31, ty = t >> 5;

    if (bid < 2048) {
        tcast_dev(Wqkv + 1024, 3072, WkvT, 1024, bid & 63, bid >> 6, tx, ty, tile);
    } else if (bid < 3072) {
        int r = bid - 2048;
        tcast_dev(Wgate, 1024, WgateT, 1024, r & 31, r >> 5, tx, ty, tile);
    } else if (bid < 4096) {
        int r = bid - 3072;
        tcast_dev(Wout, 1024, WoutT, 1024, r & 31, r >> 5, tx, ty, tile);
    } else if (bid < 5120) {
        int r = bid - 4096;
        long i = ((long)r * 256 + t) * 4;
        int row = (int)(i >> 10);
        int col = (int)(i & 1023);
        float4 f = *(const float4*)&Wqkv[(long)row * 3072 + col];
        ushort4 o;
        o.x = f2bf(f.x); o.y = f2bf(f.y); o.z = f2bf(f.z); o.w = f2bf(f.w);
        *(ushort4*)&WqC[i] = o;
    } else if (bid < 5136) {
        int r = bid - 5120;
        int nloc = t & 63, strip = t >> 6;
        int n = r * 64 + nloc;
        float s = 0.f;
        for (int j = strip * 256; j < strip * 256 + 256; j++)
            s += bqkv[j] * Wgate[(long)j * 1024 + n];
        part[strip][nloc] = s;
        __syncthreads();
        if (strip == 0)
            bfuse[n] = bgate[n] + part[0][nloc] + part[1][nloc] + part[2][nloc] + part[3][nloc];
    } else {
        const float D4T[4] = {0.4829629131445341f, 0.8365163037378079f, 0.2241438680420134f, -0.1294095225512604f};
        if (t < 2) swbuf[t] = 1.0f / (1.0f + expf(-skip_w[t]));
        if (t < 16) {
            float m = -1e30f;
            for (int j = 0; j < 16; j++) m = fmaxf(m, coupling[t * 16 + j]);
            float s = 0.f, e[16];
            for (int j = 0; j < 16; j++) { e[j] = expf(coupling[t * 16 + j] - m); s += e[j]; }
            for (int j = 0; j < 16; j++) coupS[t * 16 + j] = e[j] / s;
            float g[11];
            m = -1e30f;
            for (int j = 0; j < 11; j++) m = fmaxf(m, scale_gain[j * 16 + t]);
            s = 0.f;
            for (int j = 0; j < 11; j++) { g[j] = expf(scale_gain[j * 16 + t] - m); s += g[j]; }
            for (int j = 0; j < 11; j++) g[j] /= s;
            float cf[24];
            for (int i = 0; i < 24; i++) cf[i] = 0.f;
            for (int j = 0; j < 11; j++) {
                int d = 1 << j;
                for (int tt = 0; tt < 4; tt++) {
                    int sh = (3 - tt) * d;
                    for (int i = 0; i < 24; i++) {
                        if (SHIFTS[i] == sh) { cf[i] += g[j] * D4T[tt]; break; }
                    }
                }
            }
            for (int i = 0; i < 24; i++) coefTab[t * 24 + i] = cf[i];
        }
    }
}

// ---------------- merged: gemm64 (WfuseT = WgateT x WqC^T) + x-cast ----------------
// gemm64's 256 latency-bound blocks (bid 0..255) co-schedule under the 8192
// BW-bound cast blocks -> its ~8us hides inside the cast's memory shadow (m114
// wave-level overlap). Both consumers (fused GEMM) are downstream in-stream.
__global__ __launch_bounds__(256) void gemm64_xcast_kernel(
    const u16* __restrict__ A, const u16* __restrict__ BT,
    u16* __restrict__ C,                               // gemm64: WfuseT
    const float* __restrict__ x, u16* __restrict__ xb) {
    __shared__ u16 As[64 * 32];
    __shared__ u16 Bs[64 * 32];
    const int bid = blockIdx.x;
    const int tid = threadIdx.x;

    if (bid >= 256) {
        long i = ((long)(bid - 256) * 256 + tid) * 8;
        float4 f0 = *(const float4*)&x[i];
        float4 f1 = *(const float4*)&x[i + 4];
        u16 o[8];
        o[0] = f2bf(f0.x); o[1] = f2bf(f0.y); o[2] = f2bf(f0.z); o[3] = f2bf(f0.w);
        o[4] = f2bf(f1.x); o[5] = f2bf(f1.y); o[6] = f2bf(f1.z); o[7] = f2bf(f1.w);
        *(uint4*)&xb[i] = *(uint4*)o;
        return;
    }
    // ---- gemm64 path: 64x64 tile, 4 waves, K=1024, bf16 out ----
    const int wv = tid >> 6, lane = tid & 63;
    const int wm = wv >> 1, wn = wv & 1;          // 2x2 wave grid; wave tile 32x32
    const int lrow = lane & 15, kq = lane >> 4;
    const long m0 = (long)(bid >> 4) * 64, n0 = (long)(bid & 15) * 64;

    const int srow = wv * 16 + (lane >> 2);
    const int scol = ((lane & 3) ^ ((lane >> 3) & 3)) * 8;   // key = (srow>>1)&3 = (lane>>3)&3
    const u16* gA = A + (m0 + srow) * 1024 + scol;
    const u16* gB = BT + (n0 + srow) * 1024 + scol;
    u16* la = &As[wv * 16 * 32];
    u16* lb = &Bs[wv * 16 * 32];

    const int acol = (kq ^ ((lrow >> 1) & 3)) * 8;
    v4f acc[2][2];
#pragma unroll
    for (int i = 0; i < 2; i++)
#pragma unroll
        for (int j = 0; j < 2; j++) acc[i][j] = (v4f){0.f, 0.f, 0.f, 0.f};

    for (int k0 = 0; k0 < 1024; k0 += 32) {
        gl2lds16(gA + k0, la);
        gl2lds16(gB + k0, lb);
        __syncthreads();
        short8 af[2], bf[2];
#pragma unroll
        for (int i = 0; i < 2; i++) af[i] = *(const short8*)&As[(wm * 32 + i * 16 + lrow) * 32 + acol];
#pragma unroll
        for (int j = 0; j < 2; j++) bf[j] = *(const short8*)&Bs[(wn * 32 + j * 16 + lrow) * 32 + acol];
#pragma unroll
        for (int im = 0; im < 2; im++)
#pragma unroll
            for (int in = 0; in < 2; in++)
                acc[im][in] = __builtin_amdgcn_mfma_f32_16x16x32_bf16(af[im], bf[in], acc[im][in], 0, 0, 0);
        __syncthreads();
    }
#pragma unroll
    for (int im = 0; im < 2; im++) {
#pragma unroll
        for (int in = 0; in < 2; in++) {
            long row = m0 + wm * 32 + im * 16 + kq * 4;
            long col = n0 + wn * 32 + in * 16 + lrow;
#pragma unroll
            for (int i = 0; i < 4; i++)
                C[(row + i) * 1024 + col] = f2bf(acc[im][in][i]);
        }
    }
}

// ======== pipelined 256x256 GEMM engine (single-phase + counted vmcnt; schedule axis closed) ========
// 8 waves (2M x 4N), BK=32, 4-deep LDS tile rotation (128 KB), counted vmcnt
// (never 0 in steady state), one raw s_barrier per K-step, setprio around MFMA.
//
// CMODE=2 dataflow:
//  - k columns (n0<1024): NO stores (dead); in-register kmag only.
//  - v columns: transpose through the (free after K-loop) 128KB smem into
//    field_t layout [bh][cg][n][4], then 16B/lane coalesced copy-out.
//  - gate columns: row-major coalesced stores.
#define WAITV(N) asm volatile("s_waitcnt vmcnt(" #N ")" ::: "memory")

template <int CMODE>   // 0 = fp32 out + bias; 2 = fused field_t/gate epilogue (+kmag for k-cols)
__global__ __launch_bounds__(512, 2) void gemm256(const u16* __restrict__ A, long lda,
                                                  const u16* __restrict__ BT, long ldb, int K,
                                                  const float* __restrict__ bias,
                                                  const float* __restrict__ bias2,
                                                  void* __restrict__ C0, void* __restrict__ C1,
                                                  long ldc, float* __restrict__ kmagOut) {
    __shared__ u16 smem[4 * 2 * 8192];   // 128 KB: [buf 0..3][A|B][256 rows x 32 k]
    const int tid = threadIdx.x;
    const int wv = tid >> 6, lane = tid & 63;
    const int wm = wv >> 2, wn = wv & 3;          // 2 x 4 wave grid; wave tile 128 x 64
    const int lrow = lane & 15, kq = lane >> 4;

    // XCD-aware bijective swizzle of the dispatch-linear block id (measured neutral; kept)
    const int nwg = gridDim.x * gridDim.y;        // 768 (fused) or 256 (out): % 8 == 0
    const int lbid = blockIdx.y * gridDim.x + blockIdx.x;
    const int swz = (lbid & 7) * (nwg >> 3) + (lbid >> 3);
    const int bx = swz % gridDim.x, by = swz / gridDim.x;
    const long m0 = (long)by * 256, n0 = (long)bx * 256;

    // staging: wave wv owns rows wv*32 .. wv*32+31 of both tiles (2 calls of 16 rows each).
    // Global source column is PRE-SWIZZLED; LDS dest stays linear (gl2lds constraint).
    const int srow = wv * 32 + (lane >> 2);
    const int scol = ((lane & 3) ^ ((lane >> 3) & 3)) * 8;   // sg = (lane&3) ^ ((srow>>1)&3)
    const u16* gA0 = A + (m0 + srow) * lda + scol;
    const u16* gA1 = gA0 + 16 * lda;              // +16 rows: (row>>1)&3 unchanged
    const u16* gB0 = BT + (n0 + srow) * ldb + scol;
    const u16* gB1 = gB0 + 16 * ldb;
    const int sb = wv * 32 * 32;                  // u16 offset of wave's stage region in a tile

    // fragment read: undo the swizzle
    const int acol = (kq ^ ((lrow >> 1) & 3)) * 8;
    const int aoff = (wm * 128 + lrow) * 32 + acol;
    const int boff = (wn * 64 + lrow) * 32 + acol;

    v4f acc[8][4];
#pragma unroll
    for (int i = 0; i < 8; i++)
#pragma unroll
        for (int j = 0; j < 4; j++) acc[i][j] = (v4f){0.f, 0.f, 0.f, 0.f};

    const int NT = K >> 5;   // K-tiles of 32 (requires K >= 96; K == 1024 here)

#define STAGE256(tt) {                                              \
        const int _kk = (tt) << 5;                                  \
        u16* _p = &smem[(((tt) & 3) * 2) * 8192 + sb];              \
        gl2lds16(gA0 + _kk, _p);                                    \
        gl2lds16(gA1 + _kk, _p + 512);                              \
        gl2lds16(gB0 + _kk, _p + 8192);                             \
        gl2lds16(gB1 + _kk, _p + 8192 + 512); }

    STAGE256(0)
    STAGE256(1)
    STAGE256(2)
    WAITV(8);                        // 12 issued, <=8 outstanding -> tile 0 landed
    __builtin_amdgcn_s_barrier();

    for (int t = 0; t < NT; ++t) {
        if (t + 3 < NT) STAGE256(t + 3)          // issue-early; buffer freed at end of t-1
        const u16* Ab = &smem[((t & 3) * 2) * 8192];
        const u16* Bb = Ab + 8192;
        short8 af[8], bf[4];
#pragma unroll
        for (int i = 0; i < 8; i++) af[i] = *(const short8*)&Ab[aoff + i * 512];
#pragma unroll
        for (int j = 0; j < 4; j++) bf[j] = *(const short8*)&Bb[boff + j * 512];
        __builtin_amdgcn_s_setprio(1);
#pragma unroll
        for (int i = 0; i < 8; i++)
#pragma unroll
            for (int j = 0; j < 4; j++)
                acc[i][j] = __builtin_amdgcn_mfma_f32_16x16x32_bf16(af[i], bf[j], acc[i][j], 0, 0, 0);
        __builtin_amdgcn_s_setprio(0);
        if (t + 3 < NT)      { WAITV(8); }       // tiles t+2,t+3 may stay in flight
        else if (t + 2 < NT) { WAITV(4); }       // only t+2 issued after t+1
        else if (t + 1 < NT) { WAITV(0); }       // nothing issued after t+1: drain
        __builtin_amdgcn_s_barrier();
    }
#undef STAGE256

    // ---- epilogue ----
    if (CMODE == 0) {
        float* C = (float*)C0;
#pragma unroll
        for (int im = 0; im < 8; im++) {
#pragma unroll
            for (int in = 0; in < 4; in++) {
                long row = m0 + wm * 128 + im * 16 + kq * 4;
                long col = n0 + wn * 64 + in * 16 + lrow;
                float bv = bias ? bias[col] : 0.f;
#pragma unroll
                for (int i = 0; i < 4; i++)
                    C[(row + i) * ldc + col] = acc[im][in][i] + bv;
            }
        }
    } else {
        u16* fieldT = (u16*)C0;
        u16* gateC = (u16*)C1;
        const bool isGate = (n0 >= 2048);        // BN=256 aligns with the 2048 split
        if (isGate) {
#pragma unroll
            for (int im = 0; im < 8; im++) {
#pragma unroll
                for (int in = 0; in < 4; in++) {
                    long row = m0 + wm * 128 + im * 16 + kq * 4;
                    long gc = n0 + wn * 64 + in * 16 + lrow - 2048;
                    float bv = bias2[gc];
#pragma unroll
                    for (int i = 0; i < 4; i++) {
                        float sgm = 1.0f / (1.0f + expf(-(acc[im][in][i] + bv)));
                        gateC[(row + i) * 1024 + gc] = f2bf(sgm);
                    }
                }
            }
        } else if (n0 < 1024) {
            // k columns: kmag ONLY (k stores are dead -- nothing reads them).
            float bvv[4];
#pragma unroll
            for (int in = 0; in < 4; in++) bvv[in] = bias[n0 + wn * 64 + in * 16 + lrow];
            const int h_g = (int)(n0 >> 6) + wn;
#pragma unroll
            for (int im = 0; im < 8; im++) {
                long row = m0 + wm * 128 + im * 16 + kq * 4;
                float ss0 = 0.f, ss1 = 0.f, ss2 = 0.f, ss3 = 0.f;
#pragma unroll
                for (int in = 0; in < 4; in++) {
                    float v0 = acc[im][in][0] + bvv[in];
                    float v1 = acc[im][in][1] + bvv[in];
                    float v2 = acc[im][in][2] + bvv[in];
                    float v3 = acc[im][in][3] + bvv[in];
                    ss0 += v0 * v0; ss1 += v1 * v1; ss2 += v2 * v2; ss3 += v3 * v3;
                }
#pragma unroll
                for (int m = 1; m <= 8; m <<= 1) {
                    ss0 += __shfl_xor(ss0, m, 64);
                    ss1 += __shfl_xor(ss1, m, 64);
                    ss2 += __shfl_xor(ss2, m, 64);
                    ss3 += __shfl_xor(ss3, m, 64);
                }
                if (lrow == 0) {
                    int b = (int)(row >> 12);
                    int n = (int)(row & 4095);
                    float4 o4 = make_float4(sqrtf(ss0), sqrtf(ss1), sqrtf(ss2), sqrtf(ss3));
                    *(float4*)&kmagOut[((long)b * HH + h_g) * NSEQ + n] = o4;
                }
            }
        } else {
            // v columns: transpose through smem into field_t layout, coalesced copy-out.
            const int vc0 = (int)(n0 - 1024);
            const int h0 = vc0 >> 6;
            const int b = (int)(m0 >> 12);
            const int nn0 = (int)(m0 & 4095);
            float bvv[4];
#pragma unroll
            for (int in = 0; in < 4; in++) bvv[in] = bias[1024 + vc0 + wn * 64 + in * 16 + lrow];
            const int cpart = (lrow >> 2);       // sub-cg from lane row
            const int cch = (lrow & 3);          // channel within cg
#pragma unroll
            for (int im = 0; im < 8; im++) {
                int nl0 = wm * 128 + im * 16 + kq * 4;
#pragma unroll
                for (int in = 0; in < 4; in++) {
                    int cidx = wn * 16 + in * 4 + cpart;
                    u16* p = &smem[(cidx * 256 + nl0) * 4 + cch];
#pragma unroll
                    for (int i = 0; i < 4; i++)
                        p[i * 4] = f2bf(acc[im][in][i] + bvv[in]);
                }
            }
            __syncthreads();
#pragma unroll
            for (int it = 0; it < 16; it++) {
                int off = (it * 512 + tid) * 8;   // u16 index into the 64K-u16 LDS
                int cidx = off >> 10;             // h_local*16+cg
                int nl = (off & 1023) >> 2;       // first n_local of this 16B (even)
                u16* dst = fieldT + (((long)(b * 16 + h0 + (cidx >> 4)) * 16 + (cidx & 15)) * NSEQ + nn0 + nl) * 4;
                *(uint4*)dst = *(uint4*)&smem[off];
            }
        }
    }
}

// ---------------- pyramid: 24-tap merged dilated causal conv + fused sparse skips + kmag scale ----------------
// Stage applies field = v * kmag. Tail split: i>=6 -> n>=3072 = max shift -> guard-free.
__global__ __launch_bounds__(512) void pyramid_kernel(const u16* __restrict__ field_t,
                                                      const float* __restrict__ kmag,
                                                      const float* __restrict__ coefTab,
                                                      const float* __restrict__ swbuf,
                                                      u16* __restrict__ accp) {
    __shared__ u16 lds4[NSEQ * 4];  // 32KB: 4096 rows x 4 channels, bf16
    int blk = blockIdx.x;
    int bh = blk >> 4;       // 0..63 : b*16+h
    int cg = blk & 15;       // channel group of 4
    int hd0 = cg * 4;
    int h = bh & 15;
    int tid = threadIdx.x;

    float cf[24];
#pragma unroll
    for (int i = 0; i < 24; i++) cf[i] = coefTab[h * 24 + i];
    float sw0 = swbuf[0], sw1 = swbuf[1];

    // stage: contiguous 32 KB copy (16B per lane) with kmag scale (2 n-positions per 16B)
    const u16* src = field_t + ((long)bh * 16 + cg) * NSEQ * 4;
    const float* kmb = kmag + (long)bh * NSEQ;
#pragma unroll
    for (int k = 0; k < 4; k++) {
        long e = ((long)k * 512 + tid) * 8;
        uint4 raw = *(const uint4*)&src[e];
        int np = (int)(e >> 2);                   // first of the 2 n-positions in this 16B
        float2 km = *(const float2*)&kmb[np];
        u16 in8[8], o8[8];
        *(uint4*)in8 = raw;
#pragma unroll
        for (int q = 0; q < 4; q++) o8[q] = f2bf(bf2f(in8[q]) * km.x);
#pragma unroll
        for (int q = 4; q < 8; q++) o8[q] = f2bf(bf2f(in8[q]) * km.y);
        *(uint4*)&lds4[e] = *(uint4*)o8;
    }
    __syncthreads();

    u16* dst = accp + (long)bh * NSEQ * HD + hd0;
    float p1x = 0.f, p1y = 0.f, p1z = 0.f, p1w = 0.f;   // y at i-1 (n-512)
    float p2x = 0.f, p2y = 0.f, p2z = 0.f, p2w = 0.f;   // y at i-2 (n-1024)
    for (int i = 0; i < 6; i++) {
        int n = tid + i * 512;
        float ax = 0.f, ay = 0.f, az = 0.f, aw = 0.f;
#pragma unroll
        for (int tp = 0; tp < 24; tp++) {
            int s = SHIFTS[tp];
            if (n >= s) {
                const ushort4 f = *(const ushort4*)&lds4[(n - s) * 4];
                float c = cf[tp];
                ax += c * bf2f(f.x); ay += c * bf2f(f.y);
                az += c * bf2f(f.z); aw += c * bf2f(f.w);
            }
        }
        float ox = ax + sw0 * p1x + sw1 * p2x;
        float oy = ay + sw0 * p1y + sw1 * p2y;
        float oz = az + sw0 * p1z + sw1 * p2z;
        float ow = aw + sw0 * p1w + sw1 * p2w;
        ushort4 o;
        o.x = f2bf(ox); o.y = f2bf(oy); o.z = f2bf(oz); o.w = f2bf(ow);
        *(ushort4*)&dst[(long)n * HD] = o;
        p2x = p1x; p2y = p1y; p2z = p1z; p2w = p1w;
        p1x = ax;  p1y = ay;  p1z = az;  p1w = aw;
    }
    for (int i = 6; i < 8; i++) {                       // n >= 3072: all 24 taps valid
        int n = tid + i * 512;
        float ax = 0.f, ay = 0.f, az = 0.f, aw = 0.f;
#pragma unroll
        for (int tp = 0; tp < 24; tp++) {
            const ushort4 f = *(const ushort4*)&lds4[(n - SHIFTS[tp]) * 4];
            float c = cf[tp];
            ax += c * bf2f(f.x); ay += c * bf2f(f.y);
            az += c * bf2f(f.z); aw += c * bf2f(f.w);
        }
        float ox = ax + sw0 * p1x + sw1 * p2x;
        float oy = ay + sw0 * p1y + sw1 * p2y;
        float oz = az + sw0 * p1z + sw1 * p2z;
        float ow = aw + sw0 * p1w + sw1 * p2w;
        ushort4 o;
        o.x = f2bf(ox); o.y = f2bf(oy); o.z = f2bf(oz); o.w = f2bf(ow);
        *(ushort4*)&dst[(long)n * HD] = o;
        p2x = p1x; p2y = p1y; p2z = p1z; p2w = p1w;
        p1x = ax;  p1y = ay;  p1z = az;  p1w = aw;
    }
}

// ---------------- couple: head coupling + gate -> A3 bf16, 4 rows per block ----------------
// 4096 blocks (was 16384): accp reads become 512B contiguous runs per head,
// 4x arithmetic per thread, 1/4 the block-scheduling overhead.
__global__ __launch_bounds__(256) void couple_kernel(const u16* __restrict__ accp,
                                                     const u16* __restrict__ gate,
                                                     const float* __restrict__ coupS,
                                                     u16* __restrict__ A3) {
    __shared__ float tmp[4][DD];   // 16KB
    __shared__ float cp[256];
    int row0 = blockIdx.x * 4;     // 4 rows, same batch (4 | NSEQ)
    int b = row0 >> 12;
    int n0 = row0 & 4095;
    int tid = threadIdx.x;
    cp[tid] = coupS[tid];

    int e = tid * 4;
    int j = e >> 6;      // head
    int hd = e & 63;
    const u16* base = accp + (((long)b * HH + j) * NSEQ + n0) * HD + hd;
#pragma unroll
    for (int ni = 0; ni < 4; ni++) {
        ushort4 v0 = *(const ushort4*)(base + (long)ni * HD);
        tmp[ni][e] = bf2f(v0.x); tmp[ni][e + 1] = bf2f(v0.y);
        tmp[ni][e + 2] = bf2f(v0.z); tmp[ni][e + 3] = bf2f(v0.w);
    }
    __syncthreads();

#pragma unroll
    for (int ni = 0; ni < 4; ni++) {
        float ox = 0.f, oy = 0.f, oz = 0.f, ow = 0.f;
#pragma unroll
        for (int jj = 0; jj < 16; jj++) {
            float c = cp[j * 16 + jj];
            ox += c * tmp[ni][jj * 64 + hd];
            oy += c * tmp[ni][jj * 64 + hd + 1];
            oz += c * tmp[ni][jj * 64 + hd + 2];
            ow += c * tmp[ni][jj * 64 + hd + 3];
        }
        const ushort4 g = *(const ushort4*)&gate[(long)(row0 + ni) * DD + e];
        ox *= bf2f(g.x); oy *= bf2f(g.y); oz *= bf2f(g.z); ow *= bf2f(g.w);
        ushort4 o;
        o.x = f2bf(ox); o.y = f2bf(oy); o.z = f2bf(oz); o.w = f2bf(ow);
        *(ushort4*)&A3[(long)(row0 + ni) * DD + e] = o;
    }
}

// ---------------- launch ----------------
extern "C" void kernel_launch(void* const* d_in, const int* in_sizes, int n_in,
                              void* d_out, int out_size, void* d_ws, size_t ws_size,
                              hipStream_t stream) {
    const float* x        = (const float*)d_in[0];   // [16384][1024]
    const float* Wqkv     = (const float*)d_in[1];   // [1024][3072]
    const float* bqkv     = (const float*)d_in[2];   // [3072]
    const float* Wout     = (const float*)d_in[3];   // [1024][1024]
    const float* bout     = (const float*)d_in[4];   // [1024]
    const float* Wgate    = (const float*)d_in[5];   // [1024][1024]
    const float* bgate    = (const float*)d_in[6];   // [1024]
    const float* scale_g  = (const float*)d_in[7];   // [11][16]
    const float* skip_w   = (const float*)d_in[8];   // [2]
    const float* coupling = (const float*)d_in[9];   // [16][16]

    char* ws = (char*)d_ws;
    size_t off = 0;
    auto alloc = [&](size_t bytes) { char* p = ws + off; off += (bytes + 255) & ~(size_t)255; return p; };

    u16*   kvreg   = (u16*)alloc((size_t)MROWS * 2048 * 2);         // 67.1 MB: lo=field_t, hi=A3
    u16*   gate    = (u16*)alloc((size_t)MROWS * DD * 2);           // 33.6 MB
    u16*   reg1    = (u16*)alloc((size_t)BB * HH * NSEQ * HD * 2);  // 33.6 MB: xb, then accp
    u16*   WkvT    = (u16*)alloc((size_t)2048 * 1024 * 2);          // 4.2 MB   } contiguous: fused B^T
    u16*   WfuseT  = (u16*)alloc((size_t)1024 * 1024 * 2);          // 2.1 MB   } rows 2048..3071
    u16*   WgateT  = (u16*)alloc((size_t)1024 * 1024 * 2);          // 2.1 MB
    u16*   WoutT   = (u16*)alloc((size_t)1024 * 1024 * 2);          // 2.1 MB
    u16*   WqC     = (u16*)alloc((size_t)1024 * 1024 * 2);          // 2.1 MB
    float* kmag    = (float*)alloc((size_t)BB * HH * NSEQ * 4);     // 1.0 MB
    float* bfuse   = (float*)alloc(1024 * 4);
    float* coefT   = (float*)alloc(16 * 24 * 4);
    float* coupS   = (float*)alloc(256 * 4);
    float* swbuf   = (float*)alloc(2 * 4);
    // aliases / lifetimes:
    u16*   fieldT = kvreg;                               // written by gemm256<2> (v-cols)
    u16*   A3     = kvreg + (size_t)BB * HH * NSEQ * HD; // kv hi half
    u16*   xb     = reg1;                                // x cast; dead after gemm256<2>
    u16*   accp   = reg1;                                // pyramid out (xb dead)
    // total ~147 MB

    // 0) weights prep (small): transposes/casts, bfuse, coef tables
    prep_weights_kernel<<<5137, 256, 0, stream>>>(Wqkv, Wgate, Wout, bqkv, bgate,
                                                  scale_g, skip_w, coupling,
                                                  WkvT, WgateT, WoutT, WqC,
                                                  bfuse, coefT, coupS, swbuf);

    // 1) merged: gemm64 (WfuseT) + x-cast -- gemm64 hides under the cast's BW shadow
    gemm64_xcast_kernel<<<256 + 8192, 256, 0, stream>>>(WgateT, WqC, WfuseT, x, xb);

    // 2) fused: k->kmag only; v->field_t layout via LDS transpose (+bias); gate->sigmoid
    gemm256<2><<<dim3(12, 64), 512, 0, stream>>>(xb, 1024, WkvT, 1024, 1024,
                                                 bqkv + 1024, bfuse, fieldT, gate, 0, kmag);

    // 3) pyramid (kmag scale in stage + 24 merged taps + fused sparse skips) -> accp (xb dead)
    pyramid_kernel<<<BB * HH * 16, 512, 0, stream>>>(fieldT, kmag, coefT, swbuf, accp);

    // 4) head coupling + gating -> A3 (kv hi; fieldT dead after pyramid)
    couple_kernel<<<MROWS / 4, 256, 0, stream>>>(accp, gate, coupS, A3);

    // 5) out = A3 @ Wout + bout  (fp32 out)
    gemm256<0><<<dim3(4, 64), 512, 0, stream>>>(A3, 1024, WoutT, 1024, 1024,
                                                bout, (const float*)nullptr, (float*)d_out, nullptr,
                                                1024, (float*)nullptr);
}